// Round 12
// baseline (2573.544 us; speedup 1.0000x reference)
//
#include <hip/hip_runtime.h>

#define RNN_T 2048
#define RNN_B 64
#define RNN_H 256

typedef _Float16 f16;
typedef _Float16 f16x4 __attribute__((ext_vector_type(4)));
typedef _Float16 f16x8 __attribute__((ext_vector_type(8)));
typedef float f32x4 __attribute__((ext_vector_type(4)));

// ---------------------------------------------------------------------------
// Kernel 1: xproj[b,t,:] = embed[x[b,t]] @ Wx + b_fc   (written into hs region)
// ---------------------------------------------------------------------------
__global__ __launch_bounds__(256)
void xproj_kernel(const int* __restrict__ x, const float* __restrict__ embed,
                  const float* __restrict__ Wfc, const float* __restrict__ bfc,
                  float* __restrict__ hsb) {
    __shared__ int ixs[64];
    __shared__ __align__(16) float A[64][260];
    const int tid = threadIdx.x;
    const long rb0 = (long)blockIdx.x * 64;

    if (tid < 64) ixs[tid] = x[rb0 + tid];
    __syncthreads();

    {
        const int r = tid >> 2, q = tid & 3;
        const float* erow = embed + (long)ixs[r] * RNN_H;
        #pragma unroll
        for (int i = 0; i < 16; ++i) {
            const int c = q * 64 + i * 4;
            *(float4*)&A[r][c] = *(const float4*)(erow + c);
        }
    }
    __syncthreads();

    const int tj = tid & 31, tr = tid >> 5;
    const int r0 = tr * 8, j0 = tj * 4, j1 = 128 + tj * 4;

    float acc[8][8];
    #pragma unroll
    for (int i = 0; i < 8; ++i)
        #pragma unroll
        for (int c = 0; c < 8; ++c) acc[i][c] = 0.f;

    for (int k4 = 0; k4 < 64; ++k4) {
        float4 a[8];
        #pragma unroll
        for (int i = 0; i < 8; ++i) a[i] = *(const float4*)&A[r0 + i][k4 * 4];
        #pragma unroll
        for (int kk = 0; kk < 4; ++kk) {
            const int k = k4 * 4 + kk;
            const float4 wa = *(const float4*)(Wfc + (long)k * RNN_H + j0);
            const float4 wb = *(const float4*)(Wfc + (long)k * RNN_H + j1);
            #pragma unroll
            for (int i = 0; i < 8; ++i) {
                const float av = reinterpret_cast<const float*>(&a[i])[kk];
                acc[i][0] = fmaf(av, wa.x, acc[i][0]);
                acc[i][1] = fmaf(av, wa.y, acc[i][1]);
                acc[i][2] = fmaf(av, wa.z, acc[i][2]);
                acc[i][3] = fmaf(av, wa.w, acc[i][3]);
                acc[i][4] = fmaf(av, wb.x, acc[i][4]);
                acc[i][5] = fmaf(av, wb.y, acc[i][5]);
                acc[i][6] = fmaf(av, wb.z, acc[i][6]);
                acc[i][7] = fmaf(av, wb.w, acc[i][7]);
            }
        }
    }

    const float4 ba = *(const float4*)(bfc + j0);
    const float4 bb = *(const float4*)(bfc + j1);
    #pragma unroll
    for (int i = 0; i < 8; ++i) {
        const long row = rb0 + r0 + i;
        float4 o1 = make_float4(acc[i][0] + ba.x, acc[i][1] + ba.y,
                                acc[i][2] + ba.z, acc[i][3] + ba.w);
        float4 o2 = make_float4(acc[i][4] + bb.x, acc[i][5] + bb.y,
                                acc[i][6] + bb.z, acc[i][7] + bb.w);
        *(float4*)(hsb + row * RNN_H + j0) = o1;
        *(float4*)(hsb + row * RNN_H + j1) = o2;
    }
}

// LDS-only barrier: __syncthreads drains vmcnt(0) too; our only cross-lane
// dep is LDS, so lgkmcnt(0)+s_barrier suffices and keeps per-step global
// hs-store completion off the critical path.
#define LDS_BARRIER() asm volatile("s_waitcnt lgkmcnt(0)\n\ts_barrier" ::: "memory")

#define TANH1(d, s) { const float _e = __expf(2.f * (s));                     \
                      d = 1.f - 2.f * __builtin_amdgcn_rcpf(_e + 1.f); }

// ---------------------------------------------------------------------------
// Kernel 2: MFMA RNN scan. 4 WGs x 16 batch rows, 256 thr (4 waves, 1/SIMD).
// Mapping HW-VERIFIED by R11 (passed, absmax 4.9e-4) — kept byte-identical:
//   lane l: m = l&15 (batch row = D col), g = l>>4; wave wv owns n-tiles
//   [64wv,64wv+64); af[nt][kt] = Wh^T frags; B = H^T from swizzled LDS.
// R11 lesson: 2630 cyc/step, ~1300 of it exposed ds_read latency (bf loaded
// INSIDE the kt loop at 1 wave/SIMD -> 8 x ~130cy serial). R12:
//   (1) prefetch ALL 8 bf fragments before the MFMA block (one ~210cy wave
//       of pipelined reads instead of 8 serial exposures);
//   (2) split each n-tile acc into even/odd-kt chains (issue-bound MFMA);
//   (3) everything else unchanged.
// ---------------------------------------------------------------------------
__global__ __launch_bounds__(256, 1)
void rnn_scan_mfma(const float* __restrict__ Wfc, float* __restrict__ hsb) {
    __shared__ __align__(16) f16 hA[16 * RNN_H];
    __shared__ __align__(16) f16 hB[16 * RNN_H];
    const int tid = threadIdx.x;
    const int wg  = blockIdx.x;          // batch rows wg*16 .. +15
    const int wv = tid >> 6, l = tid & 63;
    const int m = l & 15, g = l >> 4;
    const int swz = m * 16;              // XOR swizzle (bits 4-7)

    // ---- A-fragments: af[nt][kt][i] = Wh^T[n][k] = Wh[k][n]
    const float* Wh = Wfc + RNN_H * RNN_H;
    f16x8 af[4][8];
    #pragma unroll
    for (int nt = 0; nt < 4; ++nt) {
        const int n = 64 * wv + nt * 16 + m;
        #pragma unroll
        for (int kt = 0; kt < 8; ++kt) {
            #pragma unroll
            for (int i = 0; i < 8; ++i) {
                const int k = kt * 32 + g * 8 + i;
                af[nt][kt][i] = (f16)Wh[k * RNN_H + n];
            }
        }
    }

    {   // zero h(0)
        int* z = (int*)hA;
        #pragma unroll
        for (int i = 0; i < 8; ++i) z[tid + 256 * i] = 0;
    }

    // xp / hs cursors: lane owns rows b = wg*16+m, cols n00+nt*16+{0..3}
    float* const xbase = hsb + (long)(wg * 16 + m) * RNN_T * RNN_H;
    const int n00 = 64 * wv + g * 4;

    f32x4 xr0 = *(const f32x4*)(xbase + n00 +  0);
    f32x4 xr1 = *(const f32x4*)(xbase + n00 + 16);
    f32x4 xr2 = *(const f32x4*)(xbase + n00 + 32);
    f32x4 xr3 = *(const f32x4*)(xbase + n00 + 48);
    f32x4 xn0 = *(const f32x4*)(xbase + RNN_H + n00 +  0);
    f32x4 xn1 = *(const f32x4*)(xbase + RNN_H + n00 + 16);
    f32x4 xn2 = *(const f32x4*)(xbase + RNN_H + n00 + 32);
    f32x4 xn3 = *(const f32x4*)(xbase + RNN_H + n00 + 48);

    const float* xpf  = xbase + 2 * RNN_H;            // prefetch cursor (t+2)
    const float* xend = xbase + (long)RNN_T * RNN_H;
    float*       xw   = xbase;                        // hs write cursor (t)

    char* const hAc = (char*)hA;
    char* const hBc = (char*)hB;

    __syncthreads();

#define RNN_STEP(RC, WC)                                                      \
    {                                                                         \
        /* phase 1: prefetch ALL bf fragments (independent, pipelined) */    \
        f16x8 bf[8];                                                          \
        _Pragma("unroll")                                                     \
        for (int kt = 0; kt < 8; ++kt)                                        \
            bf[kt] = *(const f16x8*)(RC + m * 512 +                           \
                                     ((kt * 64 + g * 16) ^ swz));             \
        /* phase 2: MFMA, even/odd-kt acc chains (issue-bound) */             \
        f32x4 acA0={0,0,0,0}, acA1={0,0,0,0}, acA2={0,0,0,0}, acA3={0,0,0,0}; \
        f32x4 acB0={0,0,0,0}, acB1={0,0,0,0}, acB2={0,0,0,0}, acB3={0,0,0,0}; \
        _Pragma("unroll")                                                     \
        for (int kp = 0; kp < 4; ++kp) {                                      \
            const int ke = 2 * kp, ko = 2 * kp + 1;                           \
            acA0 = __builtin_amdgcn_mfma_f32_16x16x32_f16(af[0][ke], bf[ke], acA0, 0, 0, 0); \
            acA1 = __builtin_amdgcn_mfma_f32_16x16x32_f16(af[1][ke], bf[ke], acA1, 0, 0, 0); \
            acA2 = __builtin_amdgcn_mfma_f32_16x16x32_f16(af[2][ke], bf[ke], acA2, 0, 0, 0); \
            acA3 = __builtin_amdgcn_mfma_f32_16x16x32_f16(af[3][ke], bf[ke], acA3, 0, 0, 0); \
            acB0 = __builtin_amdgcn_mfma_f32_16x16x32_f16(af[0][ko], bf[ko], acB0, 0, 0, 0); \
            acB1 = __builtin_amdgcn_mfma_f32_16x16x32_f16(af[1][ko], bf[ko], acB1, 0, 0, 0); \
            acB2 = __builtin_amdgcn_mfma_f32_16x16x32_f16(af[2][ko], bf[ko], acB2, 0, 0, 0); \
            acB3 = __builtin_amdgcn_mfma_f32_16x16x32_f16(af[3][ko], bf[ko], acB3, 0, 0, 0); \
        }                                                                     \
        /* phase 3: merge chains + xproj + tanh */                            \
        const f32x4 s0 = (acA0 + acB0) + xr0, s1 = (acA1 + acB1) + xr1;       \
        const f32x4 s2 = (acA2 + acB2) + xr2, s3 = (acA3 + acB3) + xr3;       \
        f32x4 h0, h1, h2, h3;                                                 \
        TANH1(h0.x, s0.x) TANH1(h0.y, s0.y) TANH1(h0.z, s0.z) TANH1(h0.w, s0.w) \
        TANH1(h1.x, s1.x) TANH1(h1.y, s1.y) TANH1(h1.z, s1.z) TANH1(h1.w, s1.w) \
        TANH1(h2.x, s2.x) TANH1(h2.y, s2.y) TANH1(h2.z, s2.z) TANH1(h2.w, s2.w) \
        TANH1(h3.x, s3.x) TANH1(h3.y, s3.y) TANH1(h3.z, s3.z) TANH1(h3.w, s3.w) \
        f16x4 p0, p1, p2, p3;                                                 \
        p0.x=(f16)h0.x; p0.y=(f16)h0.y; p0.z=(f16)h0.z; p0.w=(f16)h0.w;       \
        p1.x=(f16)h1.x; p1.y=(f16)h1.y; p1.z=(f16)h1.z; p1.w=(f16)h1.w;       \
        p2.x=(f16)h2.x; p2.y=(f16)h2.y; p2.z=(f16)h2.z; p2.w=(f16)h2.w;       \
        p3.x=(f16)h3.x; p3.y=(f16)h3.y; p3.z=(f16)h3.z; p3.w=(f16)h3.w;       \
        /* phase 4: LDS h-write (swizzled) + global hs store */               \
        *(f16x4*)(WC + m * 512 + (((n00 +  0) * 2) ^ swz)) = p0;              \
        *(f16x4*)(WC + m * 512 + (((n00 + 16) * 2) ^ swz)) = p1;              \
        *(f16x4*)(WC + m * 512 + (((n00 + 32) * 2) ^ swz)) = p2;              \
        *(f16x4*)(WC + m * 512 + (((n00 + 48) * 2) ^ swz)) = p3;              \
        *(f32x4*)(xw + n00 +  0) = h0;                                        \
        *(f32x4*)(xw + n00 + 16) = h1;                                        \
        *(f32x4*)(xw + n00 + 32) = h2;                                        \
        *(f32x4*)(xw + n00 + 48) = h3;                                        \
        xw += RNN_H;                                                          \
        /* phase 5: xr shift + 2-deep prefetch */                             \
        xr0 = xn0; xr1 = xn1; xr2 = xn2; xr3 = xn3;                           \
        if (xpf < xend) {                                                     \
            xn0 = *(const f32x4*)(xpf + n00 +  0);                            \
            xn1 = *(const f32x4*)(xpf + n00 + 16);                            \
            xn2 = *(const f32x4*)(xpf + n00 + 32);                            \
            xn3 = *(const f32x4*)(xpf + n00 + 48);                            \
        }                                                                     \
        xpf += RNN_H;                                                         \
        LDS_BARRIER();                                                        \
    }

    for (int t = 0; t < RNN_T; t += 2) {
        RNN_STEP(hAc, hBc);   // even: read hA, write hB
        RNN_STEP(hBc, hAc);   // odd:  read hB, write hA
    }
#undef RNN_STEP
}

// ---------------------------------------------------------------------------
// Kernel 3: out[b,:] = hs[b, T-1, :] @ W_out + b_out  (f32, from global hs)
// ---------------------------------------------------------------------------
__global__ __launch_bounds__(256)
void out_kernel(const float* __restrict__ hsb, const float* __restrict__ Wout,
                const float* __restrict__ bout, float* __restrict__ out) {
    const int b = blockIdx.x, n = threadIdx.x;
    const float* hl = hsb + ((long)b * RNN_T + (RNN_T - 1)) * RNN_H;
    float a0 = 0.f, a1 = 0.f, a2 = 0.f, a3 = 0.f;
    for (int k = 0; k < RNN_H; k += 4) {
        a0 = fmaf(hl[k + 0], Wout[(long)(k + 0) * RNN_H + n], a0);
        a1 = fmaf(hl[k + 1], Wout[(long)(k + 1) * RNN_H + n], a1);
        a2 = fmaf(hl[k + 2], Wout[(long)(k + 2) * RNN_H + n], a2);
        a3 = fmaf(hl[k + 3], Wout[(long)(k + 3) * RNN_H + n], a3);
    }
    out[(long)b * RNN_H + n] = a0 + a1 + a2 + a3 + bout[n];
}

extern "C" void kernel_launch(void* const* d_in, const int* in_sizes, int n_in,
                              void* d_out, int out_size, void* d_ws, size_t ws_size,
                              hipStream_t stream) {
    const int*   x     = (const int*)d_in[0];
    const float* embed = (const float*)d_in[1];
    const float* Wfc   = (const float*)d_in[2];
    const float* bfc   = (const float*)d_in[3];
    const float* Wout  = (const float*)d_in[4];
    const float* bout  = (const float*)d_in[5];

    float* out = (float*)d_out;                 // [B, 256]
    float* hsb = out + RNN_B * RNN_H;           // [B, T, H] region

    xproj_kernel<<<(RNN_B * RNN_T) / 64, 256, 0, stream>>>(x, embed, Wfc, bfc, hsb);
    rnn_scan_mfma<<<4, 256, 0, stream>>>(Wfc, hsb);
    out_kernel<<<RNN_B, 256, 0, stream>>>(hsb, Wout, bout, out);
}

// Round 14
// 2312.151 us; speedup vs baseline: 1.1131x; 1.1131x over previous
//
#include <hip/hip_runtime.h>

#define RNN_T 2048
#define RNN_B 64
#define RNN_H 256

typedef _Float16 f16;
typedef _Float16 f16x4 __attribute__((ext_vector_type(4)));
typedef _Float16 f16x8 __attribute__((ext_vector_type(8)));
typedef float f32x4 __attribute__((ext_vector_type(4)));

// ---------------------------------------------------------------------------
// Kernel 1: xproj[b,t,:] = embed[x[b,t]] @ Wx + b_fc   (written into hs region)
// ---------------------------------------------------------------------------
__global__ __launch_bounds__(256)
void xproj_kernel(const int* __restrict__ x, const float* __restrict__ embed,
                  const float* __restrict__ Wfc, const float* __restrict__ bfc,
                  float* __restrict__ hsb) {
    __shared__ int ixs[64];
    __shared__ __align__(16) float A[64][260];
    const int tid = threadIdx.x;
    const long rb0 = (long)blockIdx.x * 64;

    if (tid < 64) ixs[tid] = x[rb0 + tid];
    __syncthreads();

    {
        const int r = tid >> 2, q = tid & 3;
        const float* erow = embed + (long)ixs[r] * RNN_H;
        #pragma unroll
        for (int i = 0; i < 16; ++i) {
            const int c = q * 64 + i * 4;
            *(float4*)&A[r][c] = *(const float4*)(erow + c);
        }
    }
    __syncthreads();

    const int tj = tid & 31, tr = tid >> 5;
    const int r0 = tr * 8, j0 = tj * 4, j1 = 128 + tj * 4;

    float acc[8][8];
    #pragma unroll
    for (int i = 0; i < 8; ++i)
        #pragma unroll
        for (int c = 0; c < 8; ++c) acc[i][c] = 0.f;

    for (int k4 = 0; k4 < 64; ++k4) {
        float4 a[8];
        #pragma unroll
        for (int i = 0; i < 8; ++i) a[i] = *(const float4*)&A[r0 + i][k4 * 4];
        #pragma unroll
        for (int kk = 0; kk < 4; ++kk) {
            const int k = k4 * 4 + kk;
            const float4 wa = *(const float4*)(Wfc + (long)k * RNN_H + j0);
            const float4 wb = *(const float4*)(Wfc + (long)k * RNN_H + j1);
            #pragma unroll
            for (int i = 0; i < 8; ++i) {
                const float av = reinterpret_cast<const float*>(&a[i])[kk];
                acc[i][0] = fmaf(av, wa.x, acc[i][0]);
                acc[i][1] = fmaf(av, wa.y, acc[i][1]);
                acc[i][2] = fmaf(av, wa.z, acc[i][2]);
                acc[i][3] = fmaf(av, wa.w, acc[i][3]);
                acc[i][4] = fmaf(av, wb.x, acc[i][4]);
                acc[i][5] = fmaf(av, wb.y, acc[i][5]);
                acc[i][6] = fmaf(av, wb.z, acc[i][6]);
                acc[i][7] = fmaf(av, wb.w, acc[i][7]);
            }
        }
    }

    const float4 ba = *(const float4*)(bfc + j0);
    const float4 bb = *(const float4*)(bfc + j1);
    #pragma unroll
    for (int i = 0; i < 8; ++i) {
        const long row = rb0 + r0 + i;
        float4 o1 = make_float4(acc[i][0] + ba.x, acc[i][1] + ba.y,
                                acc[i][2] + ba.z, acc[i][3] + ba.w);
        float4 o2 = make_float4(acc[i][4] + bb.x, acc[i][5] + bb.y,
                                acc[i][6] + bb.z, acc[i][7] + bb.w);
        *(float4*)(hsb + row * RNN_H + j0) = o1;
        *(float4*)(hsb + row * RNN_H + j1) = o2;
    }
}

// LDS-only barrier: __syncthreads drains vmcnt(0) too; our only cross-lane
// dep is LDS, so lgkmcnt(0)+s_barrier suffices and keeps per-step global
// hs-store completion off the critical path.
#define LDS_BARRIER() asm volatile("s_waitcnt lgkmcnt(0)\n\ts_barrier" ::: "memory")

#define TANH1(d, s) { const float _e = __expf(2.f * (s));                     \
                      d = 1.f - 2.f * __builtin_amdgcn_rcpf(_e + 1.f); }

// ---------------------------------------------------------------------------
// Kernel 2: MFMA RNN scan. R12 lesson: at 1 wave/SIMD the pipes SERIALIZE
// (2750 cyc/step ~= MFMA 506 + VALU 900 + DS 300 + sync). R13/R14:
//   - 8 WGs x 8 batch rows (m-tile still 16; D cols m>=8 are garbage and
//     exec-masked) -> per-CU tanh/VALU/DS-write work halves, 8 CUs active.
//   - 8 waves/WG (2/SIMD), n-split 2 n-tiles/wave -> co-resident wave fills
//     stalls; pipe busies overlap instead of summing.
// R13 bug (NaN): zero-init wrote only 512 of 1024 ints (blockDim=512 but
// guard said tid<1024) -> LDS rows 4-7 uninitialized -> fp16-NaN garbage
// propagated from step 0. R14 fix: each thread zeros 2 ints (exactly 4KB).
// Verified R11 mapping kept: lane m=l&15 (batch col), g=l>>4;
// af[ntl][kt] = Wh^T frags (n = wv*32 + ntl*16 + m); k = kt*32+g*8+i for both
// operands (K-permutation cancels); C/D col=lane&15, row=(lane>>4)*4+reg.
// H in LDS: [8 rows][256 k] fp16, XOR swizzle keyed to row (m&7); lanes
// m>=8 read row m-8 (broadcast pair) -> harmless duplicate D cols.
// ---------------------------------------------------------------------------
__global__ __launch_bounds__(512, 2)
void rnn_scan_mfma(const float* __restrict__ Wfc, float* __restrict__ hsb) {
    __shared__ __align__(16) f16 hA[8 * RNN_H];   // 4 KB
    __shared__ __align__(16) f16 hB[8 * RNN_H];
    const int tid = threadIdx.x;
    const int wg  = blockIdx.x;          // batch rows wg*8 .. +7
    const int wv = tid >> 6, l = tid & 63;
    const int m = l & 15, g = l >> 4;
    const int mr = m & 7;                // LDS row (valid batch row index)
    const bool valid = (m < 8);
    const int swz = mr * 16;             // XOR swizzle (bits 4-6)

    // ---- A-fragments: af[ntl][kt][i] = Wh^T[n][k] = Wh[k][n]
    const float* Wh = Wfc + RNN_H * RNN_H;
    f16x8 af[2][8];
    #pragma unroll
    for (int ntl = 0; ntl < 2; ++ntl) {
        const int n = 32 * wv + ntl * 16 + m;
        #pragma unroll
        for (int kt = 0; kt < 8; ++kt) {
            #pragma unroll
            for (int i = 0; i < 8; ++i) {
                const int k = kt * 32 + g * 8 + i;
                af[ntl][kt][i] = (f16)Wh[k * RNN_H + n];
            }
        }
    }

    // zero h(0): hA is 1024 ints, blockDim 512 -> 2 ints per thread (R13 fix)
    ((int*)hA)[tid]       = 0;
    ((int*)hA)[tid + 512] = 0;

    // cursors: valid lane owns batch row wg*8+mr, cols n00 and n00+16 (+3)
    float* const xbase = hsb + (long)(wg * 8 + mr) * RNN_T * RNN_H;
    const int n00 = 32 * wv + g * 4;

    f32x4 xr0 = {0,0,0,0}, xr1 = {0,0,0,0}, xn0 = {0,0,0,0}, xn1 = {0,0,0,0};
    if (valid) {
        xr0 = *(const f32x4*)(xbase + n00);
        xr1 = *(const f32x4*)(xbase + n00 + 16);
        xn0 = *(const f32x4*)(xbase + RNN_H + n00);
        xn1 = *(const f32x4*)(xbase + RNN_H + n00 + 16);
    }
    const float* xpf  = xbase + 2 * RNN_H;            // prefetch cursor (t+2)
    const float* xend = xbase + (long)RNN_T * RNN_H;
    float*       xw   = xbase;                        // hs write cursor (t)

    char* const hAc = (char*)hA;
    char* const hBc = (char*)hB;

    __syncthreads();

#define RNN_STEP(RC, WC)                                                      \
    {                                                                         \
        f16x8 bf[8];                                                          \
        _Pragma("unroll")                                                     \
        for (int kt = 0; kt < 8; ++kt)                                        \
            bf[kt] = *(const f16x8*)(RC + mr * 512 +                          \
                                     ((kt * 64 + g * 16) ^ swz));             \
        f32x4 acA0={0,0,0,0}, acA1={0,0,0,0};                                 \
        f32x4 acB0={0,0,0,0}, acB1={0,0,0,0};                                 \
        _Pragma("unroll")                                                     \
        for (int kp = 0; kp < 4; ++kp) {                                      \
            const int ke = 2 * kp, ko = 2 * kp + 1;                           \
            acA0 = __builtin_amdgcn_mfma_f32_16x16x32_f16(af[0][ke], bf[ke], acA0, 0, 0, 0); \
            acA1 = __builtin_amdgcn_mfma_f32_16x16x32_f16(af[1][ke], bf[ke], acA1, 0, 0, 0); \
            acB0 = __builtin_amdgcn_mfma_f32_16x16x32_f16(af[0][ko], bf[ko], acB0, 0, 0, 0); \
            acB1 = __builtin_amdgcn_mfma_f32_16x16x32_f16(af[1][ko], bf[ko], acB1, 0, 0, 0); \
        }                                                                     \
        if (valid) {                                                          \
            const f32x4 s0 = (acA0 + acB0) + xr0;                             \
            const f32x4 s1 = (acA1 + acB1) + xr1;                             \
            f32x4 h0, h1;                                                     \
            TANH1(h0.x, s0.x) TANH1(h0.y, s0.y)                               \
            TANH1(h0.z, s0.z) TANH1(h0.w, s0.w)                               \
            TANH1(h1.x, s1.x) TANH1(h1.y, s1.y)                               \
            TANH1(h1.z, s1.z) TANH1(h1.w, s1.w)                               \
            f16x4 p0, p1;                                                     \
            p0.x=(f16)h0.x; p0.y=(f16)h0.y; p0.z=(f16)h0.z; p0.w=(f16)h0.w;   \
            p1.x=(f16)h1.x; p1.y=(f16)h1.y; p1.z=(f16)h1.z; p1.w=(f16)h1.w;   \
            *(f16x4*)(WC + mr * 512 + (((n00 +  0) * 2) ^ swz)) = p0;         \
            *(f16x4*)(WC + mr * 512 + (((n00 + 16) * 2) ^ swz)) = p1;         \
            *(f32x4*)(xw + n00 +  0) = h0;                                    \
            *(f32x4*)(xw + n00 + 16) = h1;                                    \
            xr0 = xn0; xr1 = xn1;                                             \
            if (xpf < xend) {                                                 \
                xn0 = *(const f32x4*)(xpf + n00);                             \
                xn1 = *(const f32x4*)(xpf + n00 + 16);                        \
            }                                                                 \
        }                                                                     \
        xw += RNN_H;                                                          \
        xpf += RNN_H;                                                         \
        LDS_BARRIER();                                                        \
    }

    for (int t = 0; t < RNN_T; t += 2) {
        RNN_STEP(hAc, hBc);   // even: read hA, write hB
        RNN_STEP(hBc, hAc);   // odd:  read hB, write hA
    }
#undef RNN_STEP
}

// ---------------------------------------------------------------------------
// Kernel 3: out[b,:] = hs[b, T-1, :] @ W_out + b_out  (f32, from global hs)
// ---------------------------------------------------------------------------
__global__ __launch_bounds__(256)
void out_kernel(const float* __restrict__ hsb, const float* __restrict__ Wout,
                const float* __restrict__ bout, float* __restrict__ out) {
    const int b = blockIdx.x, n = threadIdx.x;
    const float* hl = hsb + ((long)b * RNN_T + (RNN_T - 1)) * RNN_H;
    float a0 = 0.f, a1 = 0.f, a2 = 0.f, a3 = 0.f;
    for (int k = 0; k < RNN_H; k += 4) {
        a0 = fmaf(hl[k + 0], Wout[(long)(k + 0) * RNN_H + n], a0);
        a1 = fmaf(hl[k + 1], Wout[(long)(k + 1) * RNN_H + n], a1);
        a2 = fmaf(hl[k + 2], Wout[(long)(k + 2) * RNN_H + n], a2);
        a3 = fmaf(hl[k + 3], Wout[(long)(k + 3) * RNN_H + n], a3);
    }
    out[(long)b * RNN_H + n] = a0 + a1 + a2 + a3 + bout[n];
}

extern "C" void kernel_launch(void* const* d_in, const int* in_sizes, int n_in,
                              void* d_out, int out_size, void* d_ws, size_t ws_size,
                              hipStream_t stream) {
    const int*   x     = (const int*)d_in[0];
    const float* embed = (const float*)d_in[1];
    const float* Wfc   = (const float*)d_in[2];
    const float* bfc   = (const float*)d_in[3];
    const float* Wout  = (const float*)d_in[4];
    const float* bout  = (const float*)d_in[5];

    float* out = (float*)d_out;                 // [B, 256]
    float* hsb = out + RNN_B * RNN_H;           // [B, T, H] region

    xproj_kernel<<<(RNN_B * RNN_T) / 64, 256, 0, stream>>>(x, embed, Wfc, bfc, hsb);
    rnn_scan_mfma<<<8, 512, 0, stream>>>(Wfc, hsb);
    out_kernel<<<RNN_B, 256, 0, stream>>>(hsb, Wout, bout, out);
}

// Round 15
// 1408.923 us; speedup vs baseline: 1.8266x; 1.6411x over previous
//
#include <hip/hip_runtime.h>

#define RNN_T 2048
#define RNN_B 64
#define RNN_H 256

typedef _Float16 f16;
typedef _Float16 f16x4 __attribute__((ext_vector_type(4)));
typedef _Float16 f16x8 __attribute__((ext_vector_type(8)));
typedef float f32x4 __attribute__((ext_vector_type(4)));

// ---------------------------------------------------------------------------
// Kernel 1: xproj[b,t,:] = embed[x[b,t]] @ Wx + b_fc   (written into hs region)
// ---------------------------------------------------------------------------
__global__ __launch_bounds__(256)
void xproj_kernel(const int* __restrict__ x, const float* __restrict__ embed,
                  const float* __restrict__ Wfc, const float* __restrict__ bfc,
                  float* __restrict__ hsb) {
    __shared__ int ixs[64];
    __shared__ __align__(16) float A[64][260];
    const int tid = threadIdx.x;
    const long rb0 = (long)blockIdx.x * 64;

    if (tid < 64) ixs[tid] = x[rb0 + tid];
    __syncthreads();

    {
        const int r = tid >> 2, q = tid & 3;
        const float* erow = embed + (long)ixs[r] * RNN_H;
        #pragma unroll
        for (int i = 0; i < 16; ++i) {
            const int c = q * 64 + i * 4;
            *(float4*)&A[r][c] = *(const float4*)(erow + c);
        }
    }
    __syncthreads();

    const int tj = tid & 31, tr = tid >> 5;
    const int r0 = tr * 8, j0 = tj * 4, j1 = 128 + tj * 4;

    float acc[8][8];
    #pragma unroll
    for (int i = 0; i < 8; ++i)
        #pragma unroll
        for (int c = 0; c < 8; ++c) acc[i][c] = 0.f;

    for (int k4 = 0; k4 < 64; ++k4) {
        float4 a[8];
        #pragma unroll
        for (int i = 0; i < 8; ++i) a[i] = *(const float4*)&A[r0 + i][k4 * 4];
        #pragma unroll
        for (int kk = 0; kk < 4; ++kk) {
            const int k = k4 * 4 + kk;
            const float4 wa = *(const float4*)(Wfc + (long)k * RNN_H + j0);
            const float4 wb = *(const float4*)(Wfc + (long)k * RNN_H + j1);
            #pragma unroll
            for (int i = 0; i < 8; ++i) {
                const float av = reinterpret_cast<const float*>(&a[i])[kk];
                acc[i][0] = fmaf(av, wa.x, acc[i][0]);
                acc[i][1] = fmaf(av, wa.y, acc[i][1]);
                acc[i][2] = fmaf(av, wa.z, acc[i][2]);
                acc[i][3] = fmaf(av, wa.w, acc[i][3]);
                acc[i][4] = fmaf(av, wb.x, acc[i][4]);
                acc[i][5] = fmaf(av, wb.y, acc[i][5]);
                acc[i][6] = fmaf(av, wb.z, acc[i][6]);
                acc[i][7] = fmaf(av, wb.w, acc[i][7]);
            }
        }
    }

    const float4 ba = *(const float4*)(bfc + j0);
    const float4 bb = *(const float4*)(bfc + j1);
    #pragma unroll
    for (int i = 0; i < 8; ++i) {
        const long row = rb0 + r0 + i;
        float4 o1 = make_float4(acc[i][0] + ba.x, acc[i][1] + ba.y,
                                acc[i][2] + ba.z, acc[i][3] + ba.w);
        float4 o2 = make_float4(acc[i][4] + bb.x, acc[i][5] + bb.y,
                                acc[i][6] + bb.z, acc[i][7] + bb.w);
        *(float4*)(hsb + row * RNN_H + j0) = o1;
        *(float4*)(hsb + row * RNN_H + j1) = o2;
    }
}

// LDS-only barrier: __syncthreads drains vmcnt(0) too; our only cross-lane
// dep is LDS, so lgkmcnt(0)+s_barrier suffices and keeps per-step global
// hs-store completion off the critical path.
#define LDS_BARRIER() asm volatile("s_waitcnt lgkmcnt(0)\n\ts_barrier" ::: "memory")

// tanh via exp2 (one mul saved vs __expf(2s)); 1-2r folds to one v_fma.
#define TANH1(d, s) { const float _e = exp2f((s) * 2.885390081777927f);       \
                      d = fmaf(-2.f, __builtin_amdgcn_rcpf(_e + 1.f), 1.f); }

// ---------------------------------------------------------------------------
// Kernel 2: MFMA RNN scan. 8 WGs x 8 batch rows, 512 thr (8 waves, 2/SIMD).
// R14 post-mortem: step is VALU-ISSUE-bound (~875 cyc/SIMD, 36% active
// VALUBusy) and the epilogue ran on 32/64 lanes (masked lanes still cost
// full issue). R15 exploits the D-column duplication: lanes m>=8 feed B
// with row m-8's data, so D cols 8-15 EQUAL cols 0-7 -> lane (m,g) and
// (m+8,g) hold identical accs. SPLIT the epilogue: m<8 lanes process the
// even n-tile, m>=8 the odd n-tile. Every lane: 4 tanh, 1 cvt-quad,
// 1 ds_write_b64, 1 f32x4 global store, 1 f32x4 xr load — half of R14's
// per-wave epilogue issue, zero exec masking.
// Verified R11 mapping kept: m=l&15 (batch col), g=l>>4; af = Wh^T frags
// (n = wv*32 + ntl*16 + m); k = kt*32+g*8+i both operands; C/D col=lane&15,
// row=(lane>>4)*4+reg. H in LDS: [8 rows][256] fp16, XOR swz = mr*16.
// ---------------------------------------------------------------------------
__global__ __launch_bounds__(512, 2)
void rnn_scan_mfma(const float* __restrict__ Wfc, float* __restrict__ hsb) {
    __shared__ __align__(16) f16 hA[8 * RNN_H];   // 4 KB
    __shared__ __align__(16) f16 hB[8 * RNN_H];
    const int tid = threadIdx.x;
    const int wg  = blockIdx.x;          // batch rows wg*8 .. +7
    const int wv = tid >> 6, l = tid & 63;
    const int m = l & 15, g = l >> 4;
    const int mr = m & 7;                // LDS row / batch row index
    const bool hi = (m >= 8);            // epilogue split: hi lanes own odd tile
    const int swz = mr * 16;             // XOR swizzle (bits 4-6)

    // ---- A-fragments: af[ntl][kt][i] = Wh^T[n][k] = Wh[k][n]
    const float* Wh = Wfc + RNN_H * RNN_H;
    f16x8 af[2][8];
    #pragma unroll
    for (int ntl = 0; ntl < 2; ++ntl) {
        const int n = 32 * wv + ntl * 16 + m;
        #pragma unroll
        for (int kt = 0; kt < 8; ++kt) {
            #pragma unroll
            for (int i = 0; i < 8; ++i) {
                const int k = kt * 32 + g * 8 + i;
                af[ntl][kt][i] = (f16)Wh[k * RNN_H + n];
            }
        }
    }

    // zero h(0): hA is 1024 ints, 512 threads -> 2 ints per thread
    ((int*)hA)[tid]       = 0;
    ((int*)hA)[tid + 512] = 0;

    // per-lane cursors: batch row wg*8+mr, 4 cols at noff (even or odd tile)
    const int n00  = 32 * wv + g * 4;
    const int noff = n00 + (hi ? 16 : 0);
    float* const rowbase = hsb + (long)(wg * 8 + mr) * RNN_T * RNN_H;
    float* const xbase   = rowbase + noff;

    f32x4 xr = *(const f32x4*)(xbase);
    f32x4 xn = *(const f32x4*)(xbase + RNN_H);
    const float* xpf  = xbase + 2 * RNN_H;            // prefetch cursor (t+2)
    const float* xend = rowbase + (long)RNN_T * RNN_H;
    float*       xw   = xbase;                        // hs write cursor (t)

    const int rbyte = mr * 512;                       // LDS row byte base
    const int wbyte = rbyte + ((noff * 2) ^ swz);     // this lane's h-write slot

    char* const hAc = (char*)hA;
    char* const hBc = (char*)hB;

    __syncthreads();

#define RNN_STEP(RC, WC)                                                      \
    {                                                                         \
        f16x8 bf[8];                                                          \
        _Pragma("unroll")                                                     \
        for (int kt = 0; kt < 8; ++kt)                                        \
            bf[kt] = *(const f16x8*)(RC + rbyte +                             \
                                     ((kt * 64 + g * 16) ^ swz));             \
        f32x4 acA0={0,0,0,0}, acA1={0,0,0,0};                                 \
        f32x4 acB0={0,0,0,0}, acB1={0,0,0,0};                                 \
        _Pragma("unroll")                                                     \
        for (int kp = 0; kp < 4; ++kp) {                                      \
            const int ke = 2 * kp, ko = 2 * kp + 1;                           \
            acA0 = __builtin_amdgcn_mfma_f32_16x16x32_f16(af[0][ke], bf[ke], acA0, 0, 0, 0); \
            acA1 = __builtin_amdgcn_mfma_f32_16x16x32_f16(af[1][ke], bf[ke], acA1, 0, 0, 0); \
            acB0 = __builtin_amdgcn_mfma_f32_16x16x32_f16(af[0][ko], bf[ko], acB0, 0, 0, 0); \
            acB1 = __builtin_amdgcn_mfma_f32_16x16x32_f16(af[1][ko], bf[ko], acB1, 0, 0, 0); \
        }                                                                     \
        /* split epilogue: hi lanes take the odd n-tile (identical accs) */   \
        const f32x4 sE = acA0 + acB0;                                         \
        const f32x4 sO = acA1 + acB1;                                         \
        const f32x4 s  = (hi ? sO : sE) + xr;                                 \
        f32x4 h;                                                              \
        TANH1(h.x, s.x) TANH1(h.y, s.y) TANH1(h.z, s.z) TANH1(h.w, s.w)       \
        f16x4 p;                                                              \
        p.x = (f16)h.x; p.y = (f16)h.y; p.z = (f16)h.z; p.w = (f16)h.w;       \
        *(f16x4*)(WC + wbyte) = p;                                            \
        *(f32x4*)xw = h;                                                      \
        xw += RNN_H;                                                          \
        xr = xn;                                                              \
        if (xpf < xend) xn = *(const f32x4*)xpf;                              \
        xpf += RNN_H;                                                         \
        LDS_BARRIER();                                                        \
    }

    for (int t = 0; t < RNN_T; t += 2) {
        RNN_STEP(hAc, hBc);   // even: read hA, write hB
        RNN_STEP(hBc, hAc);   // odd:  read hB, write hA
    }
#undef RNN_STEP
}

// ---------------------------------------------------------------------------
// Kernel 3: out[b,:] = hs[b, T-1, :] @ W_out + b_out  (f32, from global hs)
// ---------------------------------------------------------------------------
__global__ __launch_bounds__(256)
void out_kernel(const float* __restrict__ hsb, const float* __restrict__ Wout,
                const float* __restrict__ bout, float* __restrict__ out) {
    const int b = blockIdx.x, n = threadIdx.x;
    const float* hl = hsb + ((long)b * RNN_T + (RNN_T - 1)) * RNN_H;
    float a0 = 0.f, a1 = 0.f, a2 = 0.f, a3 = 0.f;
    for (int k = 0; k < RNN_H; k += 4) {
        a0 = fmaf(hl[k + 0], Wout[(long)(k + 0) * RNN_H + n], a0);
        a1 = fmaf(hl[k + 1], Wout[(long)(k + 1) * RNN_H + n], a1);
        a2 = fmaf(hl[k + 2], Wout[(long)(k + 2) * RNN_H + n], a2);
        a3 = fmaf(hl[k + 3], Wout[(long)(k + 3) * RNN_H + n], a3);
    }
    out[(long)b * RNN_H + n] = a0 + a1 + a2 + a3 + bout[n];
}

extern "C" void kernel_launch(void* const* d_in, const int* in_sizes, int n_in,
                              void* d_out, int out_size, void* d_ws, size_t ws_size,
                              hipStream_t stream) {
    const int*   x     = (const int*)d_in[0];
    const float* embed = (const float*)d_in[1];
    const float* Wfc   = (const float*)d_in[2];
    const float* bfc   = (const float*)d_in[3];
    const float* Wout  = (const float*)d_in[4];
    const float* bout  = (const float*)d_in[5];

    float* out = (float*)d_out;                 // [B, 256]
    float* hsb = out + RNN_B * RNN_H;           // [B, T, H] region

    xproj_kernel<<<(RNN_B * RNN_T) / 64, 256, 0, stream>>>(x, embed, Wfc, bfc, hsb);
    rnn_scan_mfma<<<8, 512, 0, stream>>>(Wfc, hsb);
    out_kernel<<<RNN_B, 256, 0, stream>>>(hsb, Wout, bout, out);
}

// Round 16
// 1408.408 us; speedup vs baseline: 1.8273x; 1.0004x over previous
//
#include <hip/hip_runtime.h>

#define RNN_T 2048
#define RNN_B 64
#define RNN_H 256
#define KSTR 20   // floats per 16-row k-block (16 + 4 pad): 16B-aligned

typedef float v2f __attribute__((ext_vector_type(2)));

// ---------------------------------------------------------------------------
// Kernel 1: xproj[b,t,:] = embed[x[b,t]] @ Wx + b_fc   (written into hs region)
// ---------------------------------------------------------------------------
__global__ __launch_bounds__(256)
void xproj_kernel(const int* __restrict__ x, const float* __restrict__ embed,
                  const float* __restrict__ Wfc, const float* __restrict__ bfc,
                  float* __restrict__ hsb) {
    __shared__ int ixs[64];
    __shared__ __align__(16) float A[64][260];
    const int tid = threadIdx.x;
    const long rb0 = (long)blockIdx.x * 64;

    if (tid < 64) ixs[tid] = x[rb0 + tid];
    __syncthreads();

    {
        const int r = tid >> 2, q = tid & 3;
        const float* erow = embed + (long)ixs[r] * RNN_H;
        #pragma unroll
        for (int i = 0; i < 16; ++i) {
            const int c = q * 64 + i * 4;
            *(float4*)&A[r][c] = *(const float4*)(erow + c);
        }
    }
    __syncthreads();

    const int tj = tid & 31, tr = tid >> 5;
    const int r0 = tr * 8, j0 = tj * 4, j1 = 128 + tj * 4;

    float acc[8][8];
    #pragma unroll
    for (int i = 0; i < 8; ++i)
        #pragma unroll
        for (int c = 0; c < 8; ++c) acc[i][c] = 0.f;

    for (int k4 = 0; k4 < 64; ++k4) {
        float4 a[8];
        #pragma unroll
        for (int i = 0; i < 8; ++i) a[i] = *(const float4*)&A[r0 + i][k4 * 4];
        #pragma unroll
        for (int kk = 0; kk < 4; ++kk) {
            const int k = k4 * 4 + kk;
            const float4 wa = *(const float4*)(Wfc + (long)k * RNN_H + j0);
            const float4 wb = *(const float4*)(Wfc + (long)k * RNN_H + j1);
            #pragma unroll
            for (int i = 0; i < 8; ++i) {
                const float av = reinterpret_cast<const float*>(&a[i])[kk];
                acc[i][0] = fmaf(av, wa.x, acc[i][0]);
                acc[i][1] = fmaf(av, wa.y, acc[i][1]);
                acc[i][2] = fmaf(av, wa.z, acc[i][2]);
                acc[i][3] = fmaf(av, wa.w, acc[i][3]);
                acc[i][4] = fmaf(av, wb.x, acc[i][4]);
                acc[i][5] = fmaf(av, wb.y, acc[i][5]);
                acc[i][6] = fmaf(av, wb.z, acc[i][6]);
                acc[i][7] = fmaf(av, wb.w, acc[i][7]);
            }
        }
    }

    const float4 ba = *(const float4*)(bfc + j0);
    const float4 bb = *(const float4*)(bfc + j1);
    #pragma unroll
    for (int i = 0; i < 8; ++i) {
        const long row = rb0 + r0 + i;
        float4 o1 = make_float4(acc[i][0] + ba.x, acc[i][1] + ba.y,
                                acc[i][2] + ba.z, acc[i][3] + ba.w);
        float4 o2 = make_float4(acc[i][4] + bb.x, acc[i][5] + bb.y,
                                acc[i][6] + bb.z, acc[i][7] + bb.w);
        *(float4*)(hsb + row * RNN_H + j0) = o1;
        *(float4*)(hsb + row * RNN_H + j1) = o2;
    }
}

// DPP hops (VALU pipe). HW-verified R9/R10:
//   0xB1 = xor1, 0x4E = xor2, 0x128 ROW_ROR:8 = xor8, xor4 = 0x1B then 0x141.
#define DPP_HOP(val, CTRL)                                                  \
    __int_as_float(__builtin_amdgcn_update_dpp(                             \
        0, __float_as_int(val), CTRL, 0xf, 0xf, true))

__device__ __forceinline__ v2f lo2(const float4 v) { return (v2f){v.x, v.y}; }
__device__ __forceinline__ v2f hi2(const float4 v) { return (v2f){v.z, v.w}; }

// Forced packed FMA: "v" constraints REQUIRE VGPR operands, so the register
// allocator must keep the weights in arch VGPRs (R9/R10 lesson: AGPR-parked
// weights make the compiler split v_pk_fma into 2 scalar v_fma -> ~2x VALU).
#define PK_FMA(acc, h2, w2)                                                 \
    asm("v_pk_fma_f32 %0, %1, %2, %0" : "+v"(acc) : "v"(h2), "v"(w2))

// LDS-only barrier: __syncthreads drains vmcnt(0) too; our only cross-lane
// dep is LDS, so lgkmcnt(0)+s_barrier suffices and keeps the per-step global
// hs-store completion off the critical path.
#define LDS_BARRIER() asm volatile("s_waitcnt lgkmcnt(0)\n\ts_barrier" ::: "memory")

// ---------------------------------------------------------------------------
// Kernel 2: persistent VALU RNN scan (R10 structure, verified PASS, + asm
// pk_fma). One WG per batch row, 1024 threads (16 waves, 4/SIMD).
// Lane (w,l): s = l&15 -> rows k0 = s*16; col group cg = w*4 + (l>>4) ->
// 4 cols c0 = cg*4. 64 weight floats/lane as 32 v2f, consumed ONLY by
// inline-asm v_pk_fma_f32 (VGPR-forced). Per lane/step: 32 pk_fma in 4
// chains. Fused 16-way reduce + 4->1 col merge (all VALU DPP): stage1 xor1
// mux bit0, stage2 xor2 mux bit1, xor8 add (0x128), xor4 add (0x1B,0x141).
// Lane s<4 writes col c0+(s&3). DS: 4 ds_read_b128/lane, stride-20 k-blocks.
// Ping-pong h buffers; ONE LDS-only barrier/step; 2-deep xproj prefetch.
// ---------------------------------------------------------------------------
__global__ __launch_bounds__(1024, 4)
void rnn_scan_kernel(const float* __restrict__ Wfc, const float* __restrict__ Wout,
                     const float* __restrict__ bout, float* __restrict__ out,
                     float* __restrict__ hsb) {
    __shared__ __align__(16) float hA[16 * KSTR];
    __shared__ __align__(16) float hB[16 * KSTR];
    const int tid = threadIdx.x;
    const int b = blockIdx.x;
    const int w = tid >> 6, l = tid & 63;
    const int s  = l & 15;               // k-sub group: rows s*16..s*16+15
    const int cg = w * 4 + (l >> 4);     // column group 0..63
    const int c0 = cg * 4;               // 4 columns
    const int k0 = s * 16;

    // weights: wv[c][m] = {Wh[k0+2m][c0+c], Wh[k0+2m+1][c0+c]}, c<4, m<8
    const float* Wh = Wfc + RNN_H * RNN_H;
    v2f wv[4][8];
    #pragma unroll
    for (int m = 0; m < 8; ++m) {
        const long kb = (long)(k0 + 2 * m) * RNN_H;
        #pragma unroll
        for (int c = 0; c < 4; ++c) {
            v2f t;
            t.x = Wh[kb + c0 + c];
            t.y = Wh[kb + RNN_H + c0 + c];
            wv[c][m] = t;
        }
    }

    if (tid < 16 * KSTR) hA[tid] = 0.f;

    float* xpb = hsb + (long)b * RNN_T * RNN_H;
    const bool wr = (s < 4);                             // 4 writers / 16-group
    const int jcol = c0 + (s & 3);                       // writer's column
    const int widx = (jcol >> 4) * KSTR + (jcol & 15);   // LDS write slot
    float* xw = xpb + jcol;                              // hs write cursor
    const float* xpf = xpb + jcol + 2 * RNN_H;           // prefetch cursor
    const float* xend = xpb + (long)RNN_T * RNN_H;

    float xr = 0.f, xn = 0.f;
    if (wr) { xr = xpb[jcol]; xn = xpb[RNN_H + jcol]; }
    __syncthreads();

    const float4* rdA = (const float4*)(hA + s * KSTR);
    const float4* rdB = (const float4*)(hB + s * KSTR);
    const bool m1 = (l & 1), m2 = (l & 2);

#define RNN_STEP(RD, WDST)                                                  \
    {                                                                       \
        float xf = 0.f;                                                     \
        if (wr && xpf < xend) xf = *xpf;                                    \
        xpf += RNN_H;                                                       \
        const float4 q0 = RD[0], q1 = RD[1], q2 = RD[2], q3 = RD[3];        \
        const v2f hp[8] = { lo2(q0), hi2(q0), lo2(q1), hi2(q1),             \
                            lo2(q2), hi2(q2), lo2(q3), hi2(q3) };           \
        v2f a0={0,0}, a1={0,0}, a2={0,0}, a3={0,0};                         \
        _Pragma("unroll")                                                   \
        for (int m = 0; m < 8; ++m) {                                       \
            PK_FMA(a0, hp[m], wv[0][m]);                                    \
            PK_FMA(a1, hp[m], wv[1][m]);                                    \
            PK_FMA(a2, hp[m], wv[2][m]);                                    \
            PK_FMA(a3, hp[m], wv[3][m]);                                    \
        }                                                                   \
        float s0 = a0.x + a0.y, s1 = a1.x + a1.y;                           \
        float s2 = a2.x + a2.y, s3 = a3.x + a3.y;                           \
        /* stage 1: xor1 (0xB1), 4 -> 2, mux bit0 */                        \
        float b0 = (m1 ? s1 : s0) + DPP_HOP(m1 ? s0 : s1, 0xB1);            \
        float b1 = (m1 ? s3 : s2) + DPP_HOP(m1 ? s2 : s3, 0xB1);            \
        /* stage 2: xor2 (0x4E), 2 -> 1, mux bit1 */                        \
        float cv = (m2 ? b1 : b0) + DPP_HOP(m2 ? b0 : b1, 0x4E);            \
        /* stage 3: xor8 pure add (ROW_ROR:8) */                            \
        cv += DPP_HOP(cv, 0x128);                                           \
        /* stage 4: xor4 pure add via 2-hop (0x1B then 0x141) */            \
        cv += DPP_HOP(DPP_HOP(cv, 0x1B), 0x141);                            \
        if (wr) {                                                           \
            const float vsum = cv + xr;                                     \
            const float e = __expf(2.f * vsum);                             \
            const float hn = fmaf(-2.f, __builtin_amdgcn_rcpf(e + 1.f), 1.f); \
            WDST[widx] = hn;                                                \
            *xw = hn;                                                       \
            xr = xn; xn = xf;                                               \
        }                                                                   \
        xw += RNN_H;                                                        \
        LDS_BARRIER();                                                      \
    }

    for (int t = 0; t < RNN_T; t += 2) {
        RNN_STEP(rdA, hB);     // even step: read hA, write hB
        RNN_STEP(rdB, hA);     // odd step:  read hB, write hA
    }
#undef RNN_STEP

    // epilogue: out[b,:] = h_last @ W_out + b_out  (first 256 threads)
    if (tid < RNN_H) {
        const float* hl = hA;
        float a0 = 0.f, a1 = 0.f, a2 = 0.f, a3 = 0.f;
        for (int k = 0; k < RNN_H; k += 4) {
            const int kb = (k >> 4) * KSTR + (k & 15);
            a0 = fmaf(hl[kb + 0], Wout[(long)(k + 0) * RNN_H + tid], a0);
            a1 = fmaf(hl[kb + 1], Wout[(long)(k + 1) * RNN_H + tid], a1);
            a2 = fmaf(hl[kb + 2], Wout[(long)(k + 2) * RNN_H + tid], a2);
            a3 = fmaf(hl[kb + 3], Wout[(long)(k + 3) * RNN_H + tid], a3);
        }
        out[(long)b * RNN_H + tid] = a0 + a1 + a2 + a3 + bout[tid];
    }
}

extern "C" void kernel_launch(void* const* d_in, const int* in_sizes, int n_in,
                              void* d_out, int out_size, void* d_ws, size_t ws_size,
                              hipStream_t stream) {
    const int*   x     = (const int*)d_in[0];
    const float* embed = (const float*)d_in[1];
    const float* Wfc   = (const float*)d_in[2];
    const float* bfc   = (const float*)d_in[3];
    const float* Wout  = (const float*)d_in[4];
    const float* bout  = (const float*)d_in[5];

    float* out = (float*)d_out;                 // [B, 256]
    float* hsb = out + RNN_B * RNN_H;           // [B, T, H] region

    xproj_kernel<<<(RNN_B * RNN_T) / 64, 256, 0, stream>>>(x, embed, Wfc, bfc, hsb);
    rnn_scan_kernel<<<RNN_B, 1024, 0, stream>>>(Wfc, Wout, bout, out, hsb);
}

// Round 17
// 1335.505 us; speedup vs baseline: 1.9270x; 1.0546x over previous
//
#include <hip/hip_runtime.h>

#define RNN_T 2048
#define RNN_B 64
#define RNN_H 256
#define KSTR 20   // floats per 16-row k-block (16 + 4 pad): 16B-aligned

typedef float v2f __attribute__((ext_vector_type(2)));

// ---------------------------------------------------------------------------
// Kernel 1: xproj[b,t,:] = embed[x[b,t]] @ Wx + b_fc   (written into hs region)
// ---------------------------------------------------------------------------
__global__ __launch_bounds__(256)
void xproj_kernel(const int* __restrict__ x, const float* __restrict__ embed,
                  const float* __restrict__ Wfc, const float* __restrict__ bfc,
                  float* __restrict__ hsb) {
    __shared__ int ixs[64];
    __shared__ __align__(16) float A[64][260];
    const int tid = threadIdx.x;
    const long rb0 = (long)blockIdx.x * 64;

    if (tid < 64) ixs[tid] = x[rb0 + tid];
    __syncthreads();

    {
        const int r = tid >> 2, q = tid & 3;
        const float* erow = embed + (long)ixs[r] * RNN_H;
        #pragma unroll
        for (int i = 0; i < 16; ++i) {
            const int c = q * 64 + i * 4;
            *(float4*)&A[r][c] = *(const float4*)(erow + c);
        }
    }
    __syncthreads();

    const int tj = tid & 31, tr = tid >> 5;
    const int r0 = tr * 8, j0 = tj * 4, j1 = 128 + tj * 4;

    float acc[8][8];
    #pragma unroll
    for (int i = 0; i < 8; ++i)
        #pragma unroll
        for (int c = 0; c < 8; ++c) acc[i][c] = 0.f;

    for (int k4 = 0; k4 < 64; ++k4) {
        float4 a[8];
        #pragma unroll
        for (int i = 0; i < 8; ++i) a[i] = *(const float4*)&A[r0 + i][k4 * 4];
        #pragma unroll
        for (int kk = 0; kk < 4; ++kk) {
            const int k = k4 * 4 + kk;
            const float4 wa = *(const float4*)(Wfc + (long)k * RNN_H + j0);
            const float4 wb = *(const float4*)(Wfc + (long)k * RNN_H + j1);
            #pragma unroll
            for (int i = 0; i < 8; ++i) {
                const float av = reinterpret_cast<const float*>(&a[i])[kk];
                acc[i][0] = fmaf(av, wa.x, acc[i][0]);
                acc[i][1] = fmaf(av, wa.y, acc[i][1]);
                acc[i][2] = fmaf(av, wa.z, acc[i][2]);
                acc[i][3] = fmaf(av, wa.w, acc[i][3]);
                acc[i][4] = fmaf(av, wb.x, acc[i][4]);
                acc[i][5] = fmaf(av, wb.y, acc[i][5]);
                acc[i][6] = fmaf(av, wb.z, acc[i][6]);
                acc[i][7] = fmaf(av, wb.w, acc[i][7]);
            }
        }
    }

    const float4 ba = *(const float4*)(bfc + j0);
    const float4 bb = *(const float4*)(bfc + j1);
    #pragma unroll
    for (int i = 0; i < 8; ++i) {
        const long row = rb0 + r0 + i;
        float4 o1 = make_float4(acc[i][0] + ba.x, acc[i][1] + ba.y,
                                acc[i][2] + ba.z, acc[i][3] + ba.w);
        float4 o2 = make_float4(acc[i][4] + bb.x, acc[i][5] + bb.y,
                                acc[i][6] + bb.z, acc[i][7] + bb.w);
        *(float4*)(hsb + row * RNN_H + j0) = o1;
        *(float4*)(hsb + row * RNN_H + j1) = o2;
    }
}

// DPP hop on the VALU pipe. Lane-exchange facts (HW-verified R9):
//   0xB1 = xor1, 0x4E = xor2, 0x128 ROW_ROR:8 = xor8,
//   true xor4 = 0x1B then 0x141  ((i^3)^7 = i^4)
#define DPP_HOP(val, CTRL)                                                  \
    __int_as_float(__builtin_amdgcn_update_dpp(                             \
        0, __float_as_int(val), CTRL, 0xf, 0xf, true))

__device__ __forceinline__ v2f lo2(const float4 v) { return (v2f){v.x, v.y}; }
__device__ __forceinline__ v2f hi2(const float4 v) { return (v2f){v.z, v.w}; }

// LDS-only barrier: __syncthreads drains vmcnt(0) too, putting the per-step
// global hs-store / xproj-prefetch completion (~300 cyc) on every step's
// critical path. Cross-lane deps here go ONLY through LDS (hbuf), so
// lgkmcnt(0)+s_barrier suffices. Global same-lane ordering is enforced by
// the value chain (prefetched load is consumed before the same-address
// store can issue).
#define LDS_BARRIER() asm volatile("s_waitcnt lgkmcnt(0)\n\ts_barrier" ::: "memory")

// ---------------------------------------------------------------------------
// Kernel 2: persistent VALU RNN scan — R9 structure VERBATIM (best measured:
// 1153 us scan, PASS) with exactly TWO changes:
//   (1) per-step __syncthreads() -> LDS_BARRIER()  [the isolated lever]
//   (2) tanh: 1-2*rcp folded to one v_fma
// Layout: one WG per batch row, 512 threads (8 waves, 2/SIMD). Lane (w,l):
// col group cg = w*4 + (l>>4) -> 8 cols c0 = cg*8; k-sub s = l&15 -> 16 rows.
// Weights 128 floats/lane (static idx), AGPR-parked (accepted: scalar v_fma
// sources AGPRs directly — R16 proved forcing pk via asm is WORSE).
// 16-way k-reduce FUSED with 8->1 column merge (all VALU-pipe DPP):
//   stage1 xor1 mux bit0, stage2 xor2 mux bit1, stage3 xor8 mux bit3
//   (ROW_ROR:8), stage4 xor4 pure-add (0x1B then 0x141).
// Lane s ends with full sum of col c0 + ((s&3)|((s&8)?4:0)); writers (s&4)==0.
// DS: 4 ds_read_b128/lane, stride-20 k-blocks. Ping-pong h; 1 barrier/step.
// ---------------------------------------------------------------------------
__global__ __launch_bounds__(512, 2)
void rnn_scan_kernel(const float* __restrict__ Wfc, const float* __restrict__ Wout,
                     const float* __restrict__ bout, float* __restrict__ out,
                     float* __restrict__ hsb) {
    __shared__ __align__(16) float hA[16 * KSTR];
    __shared__ __align__(16) float hB[16 * KSTR];
    const int tid = threadIdx.x;
    const int b = blockIdx.x;
    const int w = tid >> 6, l = tid & 63;
    const int cg = w * 4 + (l >> 4);     // column group 0..31
    const int s  = l & 15;               // k-sub group 0..15
    const int c0 = cg * 8;               // 8 columns
    const int k0 = s * 16;               // 16 rows

    // weights: wv[c][m] = {Wh[k0+2m][c0+c], Wh[k0+2m+1][c0+c]}, c<8, m<8
    const float* Wh = Wfc + RNN_H * RNN_H;
    v2f wv[8][8];
    #pragma unroll
    for (int m = 0; m < 8; ++m) {
        const long kb = (long)(k0 + 2 * m) * RNN_H;
        #pragma unroll
        for (int c = 0; c < 8; ++c) {
            v2f t;
            t.x = Wh[kb + c0 + c];
            t.y = Wh[kb + RNN_H + c0 + c];
            wv[c][m] = t;
        }
    }
    #pragma unroll
    for (int m = 0; m < 8; ++m)
        asm volatile("" : "+v"(wv[0][m]), "+v"(wv[1][m]), "+v"(wv[2][m]), "+v"(wv[3][m]),
                          "+v"(wv[4][m]), "+v"(wv[5][m]), "+v"(wv[6][m]), "+v"(wv[7][m]));

    if (tid < 16 * KSTR) hA[tid] = 0.f;

    float* xpb = hsb + (long)b * RNN_T * RNN_H;
    const bool wr = ((s & 4) == 0);                      // 8 writers / 16-group
    const int jcol = c0 + ((s & 3) | ((s & 8) ? 4 : 0)); // lane's final column
    const int widx = (jcol >> 4) * KSTR + (jcol & 15);   // LDS write slot
    float* xw = xpb + jcol;                               // hs write cursor
    const float* xpf = xpb + jcol + 2 * RNN_H;            // prefetch cursor
    const float* xend = xpb + (long)RNN_T * RNN_H;

    float xr = 0.f, xn = 0.f;
    if (wr) { xr = xpb[jcol]; xn = xpb[RNN_H + jcol]; }
    __syncthreads();

    const float4* rdA = (const float4*)(hA + s * KSTR);
    const float4* rdB = (const float4*)(hB + s * KSTR);
    const bool m1 = (l & 1), m2 = (l & 2), m8 = (l & 8);

#define RNN_STEP(RD, WDST)                                                  \
    {                                                                       \
        float xf = 0.f;                                                     \
        if (wr && xpf < xend) xf = *xpf;                                    \
        xpf += RNN_H;                                                       \
        const float4 q0 = RD[0], q1 = RD[1], q2 = RD[2], q3 = RD[3];        \
        const v2f hp[8] = { lo2(q0), hi2(q0), lo2(q1), hi2(q1),             \
                            lo2(q2), hi2(q2), lo2(q3), hi2(q3) };           \
        v2f a0={0,0},a1={0,0},a2={0,0},a3={0,0},                            \
            a4={0,0},a5={0,0},a6={0,0},a7={0,0};                            \
        _Pragma("unroll")                                                   \
        for (int m = 0; m < 8; ++m) {                                       \
            a0 = __builtin_elementwise_fma(hp[m], wv[0][m], a0);            \
            a1 = __builtin_elementwise_fma(hp[m], wv[1][m], a1);            \
            a2 = __builtin_elementwise_fma(hp[m], wv[2][m], a2);            \
            a3 = __builtin_elementwise_fma(hp[m], wv[3][m], a3);            \
            a4 = __builtin_elementwise_fma(hp[m], wv[4][m], a4);            \
            a5 = __builtin_elementwise_fma(hp[m], wv[5][m], a5);            \
            a6 = __builtin_elementwise_fma(hp[m], wv[6][m], a6);            \
            a7 = __builtin_elementwise_fma(hp[m], wv[7][m], a7);            \
        }                                                                   \
        float s0=a0.x+a0.y, s1=a1.x+a1.y, s2=a2.x+a2.y, s3=a3.x+a3.y;       \
        float s4=a4.x+a4.y, s5=a5.x+a5.y, s6=a6.x+a6.y, s7=a7.x+a7.y;       \
        /* stage 1: xor1 (0xB1), 8 -> 4, mux bit0 */                        \
        float b0 = (m1 ? s1 : s0) + DPP_HOP(m1 ? s0 : s1, 0xB1);            \
        float b1 = (m1 ? s3 : s2) + DPP_HOP(m1 ? s2 : s3, 0xB1);            \
        float b2 = (m1 ? s5 : s4) + DPP_HOP(m1 ? s4 : s5, 0xB1);            \
        float b3 = (m1 ? s7 : s6) + DPP_HOP(m1 ? s6 : s7, 0xB1);            \
        /* stage 2: xor2 (0x4E), 4 -> 2, mux bit1 */                        \
        float c0v = (m2 ? b1 : b0) + DPP_HOP(m2 ? b0 : b1, 0x4E);           \
        float c1v = (m2 ? b3 : b2) + DPP_HOP(m2 ? b2 : b3, 0x4E);           \
        /* stage 3: xor8 (ROW_ROR:8 0x128), 2 -> 1, mux bit3 */             \
        float dv = (m8 ? c1v : c0v) + DPP_HOP(m8 ? c0v : c1v, 0x128);       \
        /* stage 4: xor4 pure add via 2-hop (0x1B then 0x141) */            \
        dv += DPP_HOP(DPP_HOP(dv, 0x1B), 0x141);                            \
        if (wr) {                                                           \
            const float vsum = dv + xr;                                     \
            const float e = __expf(2.f * vsum);                             \
            const float hn = fmaf(-2.f, __builtin_amdgcn_rcpf(e + 1.f), 1.f); \
            WDST[widx] = hn;                                                \
            *xw = hn;                                                       \
            xr = xn; xn = xf;                                               \
        }                                                                   \
        xw += RNN_H;                                                        \
        LDS_BARRIER();                                                      \
    }

    for (int t = 0; t < RNN_T; t += 2) {
        RNN_STEP(rdA, hB);     // even step: read hA, write hB
        RNN_STEP(rdB, hA);     // odd step:  read hB, write hA
    }
#undef RNN_STEP

    // epilogue: out[b,:] = h_last @ W_out + b_out  (h_last is in hA)
    if (tid < RNN_H) {
        float a0 = 0.f, a1 = 0.f, a2 = 0.f, a3 = 0.f;
        for (int k = 0; k < RNN_H; k += 4) {
            const int kb = (k >> 4) * KSTR + (k & 15);
            a0 = fmaf(hA[kb + 0], Wout[(long)(k + 0) * RNN_H + tid], a0);
            a1 = fmaf(hA[kb + 1], Wout[(long)(k + 1) * RNN_H + tid], a1);
            a2 = fmaf(hA[kb + 2], Wout[(long)(k + 2) * RNN_H + tid], a2);
            a3 = fmaf(hA[kb + 3], Wout[(long)(k + 3) * RNN_H + tid], a3);
        }
        out[(long)b * RNN_H + tid] = a0 + a1 + a2 + a3 + bout[tid];
    }
}

extern "C" void kernel_launch(void* const* d_in, const int* in_sizes, int n_in,
                              void* d_out, int out_size, void* d_ws, size_t ws_size,
                              hipStream_t stream) {
    const int*   x     = (const int*)d_in[0];
    const float* embed = (const float*)d_in[1];
    const float* Wfc   = (const float*)d_in[2];
    const float* bfc   = (const float*)d_in[3];
    const float* Wout  = (const float*)d_in[4];
    const float* bout  = (const float*)d_in[5];

    float* out = (float*)d_out;                 // [B, 256]
    float* hsb = out + RNN_B * RNN_H;           // [B, T, H] region

    xproj_kernel<<<(RNN_B * RNN_T) / 64, 256, 0, stream>>>(x, embed, Wfc, bfc, hsb);
    rnn_scan_kernel<<<RNN_B, 512, 0, stream>>>(Wfc, Wout, bout, out, hsb);
}